// Round 1
// baseline (116.003 us; speedup 1.0000x reference)
//
#include <hip/hip_runtime.h>
#include <hip/hip_bf16.h>
#include <stdint.h>

typedef __attribute__((ext_vector_type(8))) short short8;
typedef __attribute__((ext_vector_type(4))) float f32x4;
typedef unsigned short u16;

#define AS1 __attribute__((address_space(1)))
#define AS3 __attribute__((address_space(3)))

__device__ __forceinline__ u16 f2b(float f) {
  union { float f; uint32_t u; } c; c.f = f;
  uint32_t u = c.u;
  return (u16)((u + 0x7fffu + ((u >> 16) & 1u)) >> 16);  // RNE
}
__device__ __forceinline__ float b2f(u16 b) {
  union { uint32_t u; float f; } c; c.u = ((uint32_t)b) << 16;
  return c.f;
}

// ---------------- conversion kernels ----------------

__global__ void cvt_bf16_kernel(const float* __restrict__ src,
                                u16* __restrict__ dst, int n4) {
  int i = blockIdx.x * blockDim.x + threadIdx.x;
  if (i >= n4) return;
  const float4 v = reinterpret_cast<const float4*>(src)[i];
  ushort4 o;
  o.x = f2b(v.x); o.y = f2b(v.y); o.z = f2b(v.z); o.w = f2b(v.w);
  reinterpret_cast<ushort4*>(dst)[i] = o;
}

// W [K][N] f32 -> Wt [N][K] bf16 (weights are tiny, 2 MB each; L2-resident)
__global__ void cvt_transpose_kernel(const float* __restrict__ w0,
                                     const float* __restrict__ w1,
                                     const float* __restrict__ w2,
                                     u16* __restrict__ d0,
                                     u16* __restrict__ d1,
                                     u16* __restrict__ d2,
                                     int K, int N) {
  const float* src = (blockIdx.y == 0) ? w0 : (blockIdx.y == 1 ? w1 : w2);
  u16* dst = (blockIdx.y == 0) ? d0 : (blockIdx.y == 1 ? d1 : d2);
  int idx = blockIdx.x * blockDim.x + threadIdx.x;
  if (idx >= K * N) return;
  int k = idx / N, n = idx - k * N;
  dst[(size_t)n * K + k] = f2b(src[idx]);
}

// ---------------- GEMM staging ----------------
// Stage a [128 rows][32 cols] bf16 tile from row-major src (row stride
// `stride` elements) into linear LDS [128][32]. global_load_lds: LDS dest is
// wave-uniform base + lane*16; per-lane GLOBAL address supplies the data.
__device__ __forceinline__ void stage_tile(const u16* __restrict__ src, int stride,
                                           u16* lds, int wid, int lane) {
#pragma unroll
  for (int j = 0; j < 2; ++j) {
    const int lds_e = wid * 1024 + j * 512;        // element offset, wave-uniform
    const int e = lds_e + lane * 8;                // this lane's 8 bf16 (16 B)
    const int row = e >> 5;                        // 32 elems per row
    const int kk = e & 31;
    __builtin_amdgcn_global_load_lds(
        (const AS1 void*)(src + (size_t)row * stride + kk),
        (AS3 void*)(lds + lds_e), 16, 0, 0);
  }
}

// ---------------- gates kernel: Z = sigmoid(x_h @ Wz), R = sigmoid(x_h @ Wr)
// outputs: zb (bf16), rhb = R .* h_prev (bf16)
__global__ __launch_bounds__(256, 2) void gru_gates_kernel(
    const u16* __restrict__ xb,   // [B,512] bf16
    const u16* __restrict__ hb,   // [B,512] bf16
    const u16* __restrict__ wzt,  // [512,1024] bf16 (Wz^T)
    const u16* __restrict__ wrt,  // [512,1024] bf16 (Wr^T)
    const float* __restrict__ hprev,  // [B,512] f32
    u16* __restrict__ zb, u16* __restrict__ rhb) {
  __shared__ u16 As[128 * 32];
  __shared__ u16 Bz[128 * 32];
  __shared__ u16 Br[128 * 32];
  const int tid = threadIdx.x, lane = tid & 63, wid = tid >> 6;
  const int wr = wid >> 1, wc = wid & 1;
  const int bm = blockIdx.y, bn = blockIdx.x;

  f32x4 accz[4][4] = {};
  f32x4 accr[4][4] = {};

  for (int k0 = 0; k0 < 1024; k0 += 32) {
    const u16* asrc = (k0 < 512) ? (xb + (size_t)bm * 128 * 512 + k0)
                                 : (hb + (size_t)bm * 128 * 512 + (k0 - 512));
    stage_tile(asrc, 512, As, wid, lane);
    stage_tile(wzt + (size_t)bn * 128 * 1024 + k0, 1024, Bz, wid, lane);
    stage_tile(wrt + (size_t)bn * 128 * 1024 + k0, 1024, Br, wid, lane);
    __syncthreads();

    short8 a[4], bz[4], br[4];
    const int koff = (lane >> 4) * 8;
    const int rsel = lane & 15;
#pragma unroll
    for (int m = 0; m < 4; ++m)
      a[m] = *reinterpret_cast<const short8*>(&As[(wr * 64 + m * 16 + rsel) * 32 + koff]);
#pragma unroll
    for (int n = 0; n < 4; ++n) {
      bz[n] = *reinterpret_cast<const short8*>(&Bz[(wc * 64 + n * 16 + rsel) * 32 + koff]);
      br[n] = *reinterpret_cast<const short8*>(&Br[(wc * 64 + n * 16 + rsel) * 32 + koff]);
    }
#pragma unroll
    for (int m = 0; m < 4; ++m)
#pragma unroll
      for (int n = 0; n < 4; ++n) {
        accz[m][n] = __builtin_amdgcn_mfma_f32_16x16x32_bf16(a[m], bz[n], accz[m][n], 0, 0, 0);
        accr[m][n] = __builtin_amdgcn_mfma_f32_16x16x32_bf16(a[m], br[n], accr[m][n], 0, 0, 0);
      }
    __syncthreads();
  }

  // epilogue: C/D layout col=lane&15, row=(lane>>4)*4+reg
  const int col0 = bn * 128 + wc * 64 + (lane & 15);
  const int row0 = bm * 128 + wr * 64 + (lane >> 4) * 4;
#pragma unroll
  for (int m = 0; m < 4; ++m)
#pragma unroll
    for (int n = 0; n < 4; ++n)
#pragma unroll
      for (int q = 0; q < 4; ++q) {
        const int row = row0 + m * 16 + q;
        const int col = col0 + n * 16;
        const size_t idx = (size_t)row * 512 + col;
        const float z = 1.f / (1.f + __expf(-accz[m][n][q]));
        const float r = 1.f / (1.f + __expf(-accr[m][n][q]));
        const float h = hprev[idx];
        zb[idx] = f2b(z);
        rhb[idx] = f2b(r * h);
      }
}

// ---------------- candidate kernel: h_hat = tanh([x | rh] @ Wh); combine
__global__ __launch_bounds__(256, 2) void gru_cand_kernel(
    const u16* __restrict__ xb,   // [B,512] bf16
    const u16* __restrict__ rhb,  // [B,512] bf16 (r .* h_prev)
    const u16* __restrict__ wht,  // [512,1024] bf16 (Wh^T)
    const float* __restrict__ hprev,  // [B,512] f32
    const u16* __restrict__ zb,       // [B,512] bf16
    float* __restrict__ out) {
  __shared__ u16 As[128 * 32];
  __shared__ u16 Bs[128 * 32];
  const int tid = threadIdx.x, lane = tid & 63, wid = tid >> 6;
  const int wr = wid >> 1, wc = wid & 1;
  const int bm = blockIdx.y, bn = blockIdx.x;

  f32x4 acc[4][4] = {};

  for (int k0 = 0; k0 < 1024; k0 += 32) {
    const u16* asrc = (k0 < 512) ? (xb + (size_t)bm * 128 * 512 + k0)
                                 : (rhb + (size_t)bm * 128 * 512 + (k0 - 512));
    stage_tile(asrc, 512, As, wid, lane);
    stage_tile(wht + (size_t)bn * 128 * 1024 + k0, 1024, Bs, wid, lane);
    __syncthreads();

    short8 a[4], b[4];
    const int koff = (lane >> 4) * 8;
    const int rsel = lane & 15;
#pragma unroll
    for (int m = 0; m < 4; ++m)
      a[m] = *reinterpret_cast<const short8*>(&As[(wr * 64 + m * 16 + rsel) * 32 + koff]);
#pragma unroll
    for (int n = 0; n < 4; ++n)
      b[n] = *reinterpret_cast<const short8*>(&Bs[(wc * 64 + n * 16 + rsel) * 32 + koff]);
#pragma unroll
    for (int m = 0; m < 4; ++m)
#pragma unroll
      for (int n = 0; n < 4; ++n)
        acc[m][n] = __builtin_amdgcn_mfma_f32_16x16x32_bf16(a[m], b[n], acc[m][n], 0, 0, 0);
    __syncthreads();
  }

  const int col0 = bn * 128 + wc * 64 + (lane & 15);
  const int row0 = bm * 128 + wr * 64 + (lane >> 4) * 4;
#pragma unroll
  for (int m = 0; m < 4; ++m)
#pragma unroll
    for (int n = 0; n < 4; ++n)
#pragma unroll
      for (int q = 0; q < 4; ++q) {
        const int row = row0 + m * 16 + q;
        const int col = col0 + n * 16;
        const size_t idx = (size_t)row * 512 + col;
        const float s = acc[m][n][q];
        const float hh = 2.f / (1.f + __expf(-2.f * s)) - 1.f;  // tanh
        const float z = b2f(zb[idx]);
        const float h = hprev[idx];
        out[idx] = z * h + (1.f - z) * hh;
      }
}

// ---------------- launch ----------------
extern "C" void kernel_launch(void* const* d_in, const int* in_sizes, int n_in,
                              void* d_out, int out_size, void* d_ws, size_t ws_size,
                              hipStream_t stream) {
  const float* inputs = (const float*)d_in[0];
  const float* h_prev = (const float*)d_in[1];
  const float* Wz = (const float*)d_in[2];
  const float* Wr = (const float*)d_in[3];
  const float* Wh = (const float*)d_in[4];
  float* out = (float*)d_out;

  const int B = 16384, D = 512, U = 512, K = 1024;

  u16* xb = (u16*)d_ws;                 // [B,D] bf16
  u16* hb = xb + (size_t)B * D;         // [B,U] bf16
  u16* wzt = hb + (size_t)B * U;        // [U,K] bf16
  u16* wrt = wzt + (size_t)K * U;
  u16* wht = wrt + (size_t)K * U;
  u16* zb = wht + (size_t)K * U;        // [B,U] bf16
  u16* rhb = zb + (size_t)B * U;        // [B,U] bf16

  const int n4 = (B * D) / 4;
  cvt_bf16_kernel<<<(n4 + 255) / 256, 256, 0, stream>>>(inputs, xb, n4);
  cvt_bf16_kernel<<<(n4 + 255) / 256, 256, 0, stream>>>(h_prev, hb, n4);
  dim3 tg((K * U + 255) / 256, 3);
  cvt_transpose_kernel<<<tg, 256, 0, stream>>>(Wz, Wr, Wh, wzt, wrt, wht, K, U);

  dim3 g(U / 128, B / 128);  // (4, 128) = 512 blocks
  gru_gates_kernel<<<g, 256, 0, stream>>>(xb, hb, wzt, wrt, h_prev, zb, rhb);
  gru_cand_kernel<<<g, 256, 0, stream>>>(xb, rhb, wht, h_prev, zb, out);
}

// Round 3
// 106.715 us; speedup vs baseline: 1.0870x; 1.0870x over previous
//
#include <hip/hip_runtime.h>
#include <hip/hip_bf16.h>
#include <stdint.h>

typedef __attribute__((ext_vector_type(8))) short short8;
typedef __attribute__((ext_vector_type(4))) float f32x4;
typedef unsigned short u16;

#define AS1 __attribute__((address_space(1)))
#define AS3 __attribute__((address_space(3)))

__device__ __forceinline__ u16 f2b(float f) {
  union { float f; uint32_t u; } c; c.f = f;
  uint32_t u = c.u;
  return (u16)((u + 0x7fffu + ((u >> 16) & 1u)) >> 16);  // RNE
}
__device__ __forceinline__ float b2f(u16 b) {
  union { uint32_t u; float f; } c; c.u = ((uint32_t)b) << 16;
  return c.f;
}

// ---------------- conversion kernels (verified round 1) ----------------
__global__ void cvt_bf16_kernel(const float* __restrict__ src,
                                u16* __restrict__ dst, int n4) {
  int i = blockIdx.x * blockDim.x + threadIdx.x;
  if (i >= n4) return;
  const float4 v = reinterpret_cast<const float4*>(src)[i];
  ushort4 o;
  o.x = f2b(v.x); o.y = f2b(v.y); o.z = f2b(v.z); o.w = f2b(v.w);
  reinterpret_cast<ushort4*>(dst)[i] = o;
}

__global__ void cvt_transpose_kernel(const float* __restrict__ w0,
                                     const float* __restrict__ w1,
                                     const float* __restrict__ w2,
                                     u16* __restrict__ d0,
                                     u16* __restrict__ d1,
                                     u16* __restrict__ d2,
                                     int K, int N) {
  const float* src = (blockIdx.y == 0) ? w0 : (blockIdx.y == 1 ? w1 : w2);
  u16* dst = (blockIdx.y == 0) ? d0 : (blockIdx.y == 1 ? d1 : d2);
  int idx = blockIdx.x * blockDim.x + threadIdx.x;
  if (idx >= K * N) return;
  int k = idx / N, n = idx - k * N;
  dst[(size_t)n * K + k] = f2b(src[idx]);
}

// ---------------- triple-buffered, 2-tile-ahead pipelined GEMM ----------
// C[16384,N] = A[.,1024] @ Wt[N][1024]^T.  BM=256, BK=32, NT=32 K-tiles.
// 512 thr = 8 waves (2M x 4N); per-wave 128 x (BN/4) output.
// LDS: 3 buffers of (A 16KB + B BN*64B). During tile kt we issue ALL stage
// insts for tile kt+2 into buf[(kt+2)%3]; end-of-tile wait vmcnt(TI) leaves
// only those TI just-issued loads outstanding => tile kt+1 fully landed
// before the barrier releases any reader. buf[(kt+2)%3]==buf[(kt-1)%3] was
// last read before the PREVIOUS barrier => no WAR hazard. One barrier/tile.
// LDS swizzle (64B rows = 4 x 16B slots): slot ^= (row>>1)&3, applied on the
// global source (linear global_load_lds dest) AND on ds_read addresses.

#define BAR() do { __builtin_amdgcn_s_barrier(); __builtin_amdgcn_sched_barrier(0); } while (0)
#define VMW(n) asm volatile("s_waitcnt vmcnt(" #n ")" ::: "memory")

template <int BN, int EPI>
__global__ __launch_bounds__(512, 1) void gemm_kernel(
    const u16* __restrict__ a1,   // A cols 0..511    [16384,512] bf16
    const u16* __restrict__ a2,   // A cols 512..1023 [16384,512] bf16
    const u16* __restrict__ wt,   // weights^T [N][1024] bf16
    const float* __restrict__ hprev,  // h_prev f32 [16384,512]
    const u16* __restrict__ zb_in,    // z bf16 (EPI=1)
    u16* __restrict__ o_z,        // EPI=0
    u16* __restrict__ o_rh,       // EPI=0
    float* __restrict__ o_f) {    // EPI=1
  constexpr int NT = 32;
  constexpr int NF = BN / 64;          // n-frags per wave (4 or 2)
  constexpr int ATILE_E = 8192;        // A tile u16 count (256x32)
  constexpr int BTILE_E = BN * 32;
  constexpr int BUF_E = ATILE_E + BTILE_E;

  __shared__ u16 lds[3 * BUF_E];

  const int tid = threadIdx.x;
  const int lane = tid & 63;
  const int wid = tid >> 6;
  const int wm = wid >> 2;
  const int wn = wid & 3;

  // XCD-chunked bijective swizzle (grid = 256 = 8*32)
  const int wg = ((int)blockIdx.x & 7) * 32 + ((int)blockIdx.x >> 3);
  const int bn = wg & 3;
  const int bm = wg >> 2;

  // ---- staging addresses.  Each stage inst: 512 lanes x 16B = 8192 B =
  // 128 rows x 64 B.  LDS row = i*128 + wid*16 + (lane>>2), slot = lane&3.
  // Source slot = slot ^ ((row>>1)&3) = (lane&3) ^ ((lane>>3)&3).
  const int srow = wid * 16 + (lane >> 2);
  const int scol = ((lane & 3) ^ ((lane >> 3) & 3)) << 4;   // bytes
  const size_t aoff = (size_t)srow * 1024 + scol;           // A row = 1024 B
  const size_t boff = (size_t)srow * 2048 + scol;           // B row = 2048 B
  const size_t abase_g = (size_t)bm * 262144;               // bm*256 rows
  const size_t bbase_g = (size_t)bn * BN * 2048;

  auto STAGE = [&](int ktn, u16* buf) {
    const char* asn = (ktn < 16) ? ((const char*)a1 + abase_g + (size_t)ktn * 64)
                                 : ((const char*)a2 + abase_g + (size_t)(ktn - 16) * 64);
    const char* bsn = (const char*)wt + bbase_g + (size_t)ktn * 64;
    __builtin_amdgcn_global_load_lds((const AS1 void*)(asn + aoff),
                                     (AS3 void*)(buf + wid * 512), 16, 0, 0);
    __builtin_amdgcn_global_load_lds((const AS1 void*)(asn + 131072 + aoff),
                                     (AS3 void*)(buf + 4096 + wid * 512), 16, 0, 0);
    __builtin_amdgcn_global_load_lds((const AS1 void*)(bsn + boff),
                                     (AS3 void*)(buf + ATILE_E + wid * 512), 16, 0, 0);
    if constexpr (BN == 256)
      __builtin_amdgcn_global_load_lds((const AS1 void*)(bsn + 262144 + boff),
                                       (AS3 void*)(buf + ATILE_E + 4096 + wid * 512), 16, 0, 0);
  };

  // ---- frag-read addresses (swizzled).  16x16x32 frag: lane = kg*16+rsel,
  // reads row (base+rsel), k-slot kg.  row>>1&3 == (rsel>>1)&3.
  const int rsel = lane & 15;
  const int kg = lane >> 4;
  const int rcol = (kg ^ ((rsel >> 1) & 3)) << 4;
  const int abyte = (wm * 128 + rsel) * 64 + rcol;               // + mf*1024
  const int bbyte = 16384 + (wn * (BN / 4) + rsel) * 64 + rcol;  // + nf*1024

  f32x4 acc[8][NF] = {};

  // prologue: tiles 0 and 1 in flight; wait tile 0 landed
  STAGE(0, lds);
  STAGE(1, lds + BUF_E);
  if constexpr (BN == 256) VMW(4); else VMW(3);
  BAR();

  int cb = 0;
  for (int kt = 0; kt < NT; ++kt) {
    u16* cur = lds + cb * BUF_E;
    const bool st = (kt + 2) < NT;
    if (st) {
      int nb = cb + 2; if (nb >= 3) nb -= 3;
      STAGE(kt + 2, lds + nb * BUF_E);
    }
    short8 bv[NF];
#pragma unroll
    for (int nf = 0; nf < NF; ++nf)
      bv[nf] = *(const short8*)((const char*)cur + bbyte + nf * 1024);
    __builtin_amdgcn_s_setprio(1);
#pragma unroll
    for (int mf = 0; mf < 8; ++mf) {
      const short8 av = *(const short8*)((const char*)cur + abyte + mf * 1024);
#pragma unroll
      for (int nf = 0; nf < NF; ++nf)
        acc[mf][nf] = __builtin_amdgcn_mfma_f32_16x16x32_bf16(av, bv[nf], acc[mf][nf], 0, 0, 0);
    }
    __builtin_amdgcn_s_setprio(0);
    if (st) {
      if constexpr (BN == 256) VMW(4); else VMW(3);   // kt+1 loads all landed
    } else {
      VMW(0);                                          // tail drain
    }
    BAR();
    ++cb; if (cb == 3) cb = 0;
  }

  // ---- epilogue.  C/D: col = rsel (B-row), row = kg*4 + q (A-row).
  const int row0 = bm * 256 + wm * 128 + kg * 4;
  const int col0 = bn * BN + wn * (BN / 4) + rsel;
  if constexpr (EPI == 0) {
    if (bn < 2) {  // z half (global cols 0..511), block-uniform branch
#pragma unroll
      for (int mf = 0; mf < 8; ++mf)
#pragma unroll
        for (int nf = 0; nf < NF; ++nf)
#pragma unroll
          for (int q = 0; q < 4; ++q) {
            const int row = row0 + mf * 16 + q;
            const int col = col0 + nf * 16;
            const float zf = 1.f / (1.f + __expf(-acc[mf][nf][q]));
            o_z[(size_t)row * 512 + col] = f2b(zf);
          }
    } else {       // r half (global cols 512..1023)
#pragma unroll
      for (int mf = 0; mf < 8; ++mf)
#pragma unroll
        for (int nf = 0; nf < NF; ++nf)
#pragma unroll
          for (int q = 0; q < 4; ++q) {
            const int row = row0 + mf * 16 + q;
            const int col = col0 + nf * 16 - 512;
            const size_t idx = (size_t)row * 512 + col;
            const float rf = 1.f / (1.f + __expf(-acc[mf][nf][q]));
            o_rh[idx] = f2b(rf * hprev[idx]);
          }
    }
  } else {
#pragma unroll
    for (int mf = 0; mf < 8; ++mf)
#pragma unroll
      for (int nf = 0; nf < NF; ++nf)
#pragma unroll
        for (int q = 0; q < 4; ++q) {
          const int row = row0 + mf * 16 + q;
          const int col = col0 + nf * 16;
          const size_t idx = (size_t)row * 512 + col;
          const float s = acc[mf][nf][q];
          const float hh = 2.f / (1.f + __expf(-2.f * s)) - 1.f;  // tanh
          const float z = b2f(zb_in[idx]);
          o_f[idx] = z * hprev[idx] + (1.f - z) * hh;
        }
  }
}

// ---------------- launch ----------------
extern "C" void kernel_launch(void* const* d_in, const int* in_sizes, int n_in,
                              void* d_out, int out_size, void* d_ws, size_t ws_size,
                              hipStream_t stream) {
  const float* inputs = (const float*)d_in[0];
  const float* h_prev = (const float*)d_in[1];
  const float* Wz = (const float*)d_in[2];
  const float* Wr = (const float*)d_in[3];
  const float* Wh = (const float*)d_in[4];
  float* out = (float*)d_out;

  const int B = 16384, D = 512, U = 512, K = 1024;

  u16* xb = (u16*)d_ws;                 // [B,D] bf16
  u16* hb = xb + (size_t)B * D;         // [B,U] bf16
  u16* wzt = hb + (size_t)B * U;        // [1024,1024]: rows 0-511 Wz^T, 512-1023 Wr^T
  u16* wrt = wzt + (size_t)K * U;
  u16* wht = wrt + (size_t)K * U;       // [512,1024] Wh^T
  u16* zb = wht + (size_t)K * U;        // [B,U] bf16
  u16* rhb = zb + (size_t)B * U;        // [B,U] bf16

  const int n4 = (B * D) / 4;
  cvt_bf16_kernel<<<(n4 + 255) / 256, 256, 0, stream>>>(inputs, xb, n4);
  cvt_bf16_kernel<<<(n4 + 255) / 256, 256, 0, stream>>>(h_prev, hb, n4);
  dim3 tg((K * U + 255) / 256, 3);
  cvt_transpose_kernel<<<tg, 256, 0, stream>>>(Wz, Wr, Wh, wzt, wrt, wht, K, U);

  // gates: N=1024 (z|r), BN=256 -> grid 64*4 = 256 blocks
  gemm_kernel<256, 0><<<dim3(256), 512, 0, stream>>>(xb, hb, wzt, h_prev, nullptr, zb, rhb, nullptr);
  // candidate: N=512, BN=128 -> grid 64*4 = 256 blocks
  gemm_kernel<128, 1><<<dim3(256), 512, 0, stream>>>(xb, rhb, wht, h_prev, zb, nullptr, nullptr, out);
}